// Round 1
// baseline (209.248 us; speedup 1.0000x reference)
//
#include <hip/hip_runtime.h>

#define BS 16
#define SEQL 2048
#define NH 16
#define PD 64
#define ND 16
#define LB 64
#define NC 32   // SEQL / LB

// ------------------------------------------------------------------
// K1: per (b,h,c): cumsum(A) within chunk; chunk state
//     S[p][n] = sum_l B[l,n] * exp(Asum - Acs[l]) * X[l,p]
// ------------------------------------------------------------------
__global__ __launch_bounds__(256) void k1_state(
    const float* __restrict__ Xg, const float* __restrict__ Ag,
    const float* __restrict__ Bg, float* __restrict__ Sg,
    float* __restrict__ ACSg) {
  const int bhc = blockIdx.x;
  const int c  = bhc & (NC - 1);
  const int bh = bhc >> 5;
  const int h  = bh & (NH - 1);
  const int b  = bh >> 4;
  __shared__ float sAcs[LB];
  __shared__ float sBd[LB][ND];
  __shared__ float sX[LB][PD];
  const int t = threadIdx.x;

  if (t < 64) {
    float v = Ag[((size_t)(b * SEQL) + c * LB + t) * NH + h];
#pragma unroll
    for (int d = 1; d < 64; d <<= 1) {
      float o = __shfl_up(v, d, 64);
      if (t >= d) v += o;
    }
    sAcs[t] = v;
    ACSg[(((size_t)b * NC + c) * NH + h) * LB + t] = v;
  }
  __syncthreads();
  const float total = sAcs[LB - 1];
  {
    const int l = t >> 2, q = t & 3;
    float4 b4 = *(const float4*)&Bg[((((size_t)(b * SEQL) + c * LB + l) * NH + h) * ND) + q * 4];
    const float dec = expf(total - sAcs[l]);
    b4.x *= dec; b4.y *= dec; b4.z *= dec; b4.w *= dec;
    ((float4*)sBd[l])[q] = b4;
  }
  {
    const int s = t >> 2, p0 = (t & 3) * 16;
    const float4* src = (const float4*)&Xg[((((size_t)(b * SEQL) + c * LB + s) * NH + h) * PD) + p0];
    float4* dst = (float4*)&sX[s][p0];
#pragma unroll
    for (int k = 0; k < 4; ++k) dst[k] = src[k];
  }
  __syncthreads();
  const int p = t >> 2, nq = t & 3;
  float4 acc = make_float4(0.f, 0.f, 0.f, 0.f);
#pragma unroll
  for (int l = 0; l < LB; ++l) {
    const float x = sX[l][p];
    const float4 b4 = ((const float4*)sBd[l])[nq];
    acc.x += x * b4.x; acc.y += x * b4.y; acc.z += x * b4.z; acc.w += x * b4.w;
  }
  // element (p, n0+k) = 4*t + k  -> fully coalesced float4 store
  ((float4*)&Sg[(((size_t)b * NC + c) * NH + h) * (PD * ND)])[t] = acc;
}

// ------------------------------------------------------------------
// K2: per (b,h): inter-chunk scan
//     ST[c] = ST[c-1]*exp(Asum[c-1]) + S[c-1],  ST[0] = 0
// ------------------------------------------------------------------
__global__ __launch_bounds__(1024) void k2_scan(
    const float* __restrict__ Sg, const float* __restrict__ ACSg,
    float* __restrict__ STg) {
  const int bh = blockIdx.x;
  const int h = bh & (NH - 1);
  const int b = bh >> 4;
  __shared__ float sE[NC];
  const int t = threadIdx.x;
  if (t < NC)
    sE[t] = expf(ACSg[(((size_t)b * NC + t) * NH + h) * LB + (LB - 1)]);
  __syncthreads();
  float st = 0.f;
  for (int c = 0; c < NC; ++c) {
    const size_t off = (((size_t)b * NC + c) * NH + h) * (PD * ND) + t;
    STg[off] = st;
    st = st * sE[c] + Sg[off];
  }
}

// ------------------------------------------------------------------
// K3: per (b,h,c): M[l][s] = exp(Acs[l]-Acs[s]) * <C[l],B[s]>  (s<=l)
//     Y[l][p] = sum_s M[l][s]*X[s][p] + exp(Acs[l]) * <C[l], ST[p,:]>
// ------------------------------------------------------------------
__global__ __launch_bounds__(256) void k3_out(
    const float* __restrict__ Xg, const float* __restrict__ Bg,
    const float* __restrict__ Cg, const float* __restrict__ ACSg,
    const float* __restrict__ STg, float* __restrict__ Yg) {
  const int bhc = blockIdx.x;
  const int c  = bhc & (NC - 1);
  const int bh = bhc >> 5;
  const int h  = bh & (NH - 1);
  const int b  = bh >> 4;
  __shared__ float sC[LB][ND];
  __shared__ float sB[LB][ND];
  __shared__ float sX[LB][PD];
  __shared__ float sM[LB][LB + 1];   // +1 pad: l-indexed reads hit distinct banks
  __shared__ float sST[PD][ND];
  __shared__ float sAcs[LB];
  __shared__ float sE[LB];
  const int t = threadIdx.x;

  if (t < 64) {
    const float v = ACSg[(((size_t)b * NC + c) * NH + h) * LB + t];
    sAcs[t] = v;
    sE[t] = expf(v);
  }
  {
    const int l = t >> 2, q = t & 3;
    const size_t base = (((size_t)(b * SEQL) + c * LB + l) * NH + h) * ND;
    ((float4*)sC[l])[q] = *(const float4*)&Cg[base + q * 4];
    ((float4*)sB[l])[q] = *(const float4*)&Bg[base + q * 4];
  }
  {
    const int s = t >> 2, p0 = (t & 3) * 16;
    const float4* src = (const float4*)&Xg[((((size_t)(b * SEQL) + c * LB + s) * NH + h) * PD) + p0];
    float4* dst = (float4*)&sX[s][p0];
#pragma unroll
    for (int k = 0; k < 4; ++k) dst[k] = src[k];
  }
  ((float4*)sST)[t] = ((const float4*)&STg[(((size_t)b * NC + c) * NH + h) * (PD * ND)])[t];
  __syncthreads();

  // phase 1: build M (lower triangular, zeros above diagonal)
  {
    const int l = t >> 2, s0 = (t & 3) * 16;
    float4 c4[4];
#pragma unroll
    for (int q = 0; q < 4; ++q) c4[q] = ((const float4*)sC[l])[q];
    const float al = sAcs[l];
    for (int j = 0; j < 16; ++j) {
      const int s = s0 + j;
      float m = 0.f;
      if (s <= l) {
        float d = 0.f;
#pragma unroll
        for (int q = 0; q < 4; ++q) {
          const float4 b4 = ((const float4*)sB[s])[q];
          d += c4[q].x * b4.x + c4[q].y * b4.y + c4[q].z * b4.z + c4[q].w * b4.w;
        }
        m = expf(al - sAcs[s]) * d;
      }
      sM[l][s] = m;
    }
  }
  __syncthreads();

  // phase 2: Y = M @ X + exp(Acs) * (C @ ST^T)
  {
    const int l = t >> 2, p0 = (t & 3) * 16;
    float4 acc[4];
#pragma unroll
    for (int k = 0; k < 4; ++k) acc[k] = make_float4(0.f, 0.f, 0.f, 0.f);
    // wave w holds l in [16w,16w+16) -> only s < 16(w+1) can be nonzero
    const int smax = ((t >> 6) + 1) << 4;
    for (int s = 0; s < smax; ++s) {
      const float m = sM[l][s];
#pragma unroll
      for (int k = 0; k < 4; ++k) {
        const float4 x4 = ((const float4*)&sX[s][p0])[k];
        acc[k].x += m * x4.x; acc[k].y += m * x4.y;
        acc[k].z += m * x4.z; acc[k].w += m * x4.w;
      }
    }
    // Y_off
    float4 c4[4];
#pragma unroll
    for (int q = 0; q < 4; ++q) c4[q] = ((const float4*)sC[l])[q];
    const float el = sE[l];
#pragma unroll
    for (int k = 0; k < 4; ++k) {
      float o[4];
#pragma unroll
      for (int cmp = 0; cmp < 4; ++cmp) {
        const int p = p0 + k * 4 + cmp;
        float d = 0.f;
#pragma unroll
        for (int q = 0; q < 4; ++q) {
          const float4 s4 = ((const float4*)sST[p])[q];
          d += c4[q].x * s4.x + c4[q].y * s4.y + c4[q].z * s4.z + c4[q].w * s4.w;
        }
        o[cmp] = d;
      }
      acc[k].x += el * o[0]; acc[k].y += el * o[1];
      acc[k].z += el * o[2]; acc[k].w += el * o[3];
    }
    float4* dst = (float4*)&Yg[((((size_t)(b * SEQL) + c * LB + l) * NH + h) * PD) + p0];
#pragma unroll
    for (int k = 0; k < 4; ++k) dst[k] = acc[k];
  }
}

extern "C" void kernel_launch(void* const* d_in, const int* in_sizes, int n_in,
                              void* d_out, int out_size, void* d_ws, size_t ws_size,
                              hipStream_t stream) {
  (void)in_sizes; (void)n_in; (void)out_size; (void)ws_size;
  const float* X = (const float*)d_in[0];
  const float* A = (const float*)d_in[1];
  const float* B = (const float*)d_in[2];
  const float* C = (const float*)d_in[3];
  float* Y = (float*)d_out;

  const size_t SZ = (size_t)BS * NC * NH * PD * ND;  // 524288 floats
  float* Sg   = (float*)d_ws;
  float* STg  = Sg + SZ;
  float* ACSg = STg + SZ;   // BS*NC*NH*LB = 524288 floats

  k1_state<<<BS * NH * NC, 256, 0, stream>>>(X, A, B, Sg, ACSg);
  k2_scan<<<BS * NH, 1024, 0, stream>>>(Sg, ACSg, STg);
  k3_out<<<BS * NH * NC, 256, 0, stream>>>(X, B, C, ACSg, STg, Y);
}

// Round 2
// 114.438 us; speedup vs baseline: 1.8285x; 1.8285x over previous
//
#include <hip/hip_runtime.h>

#define BS 16
#define SEQL 2048
#define NH 16
#define PD 64
#define ND 16
#define LB 64
#define NC 32   // SEQL / LB

typedef __attribute__((ext_vector_type(8))) short bf16x8;
typedef __attribute__((ext_vector_type(4))) float f32x4;

static __device__ __forceinline__ unsigned short f2bf(float x) {
  unsigned int u = __float_as_uint(x);
  unsigned int r = (u + 0x7FFFu + ((u >> 16) & 1u)) >> 16;  // RNE
  return (unsigned short)r;
}

// ------------------------------------------------------------------
// K1: per (b,h,c): cumsum(A) within chunk; chunk state
//     S[p][n] = sum_l B[l,n] * exp(Asum - Acs[l]) * X[l,p]
// ------------------------------------------------------------------
__global__ __launch_bounds__(256) void k1_state(
    const float* __restrict__ Xg, const float* __restrict__ Ag,
    const float* __restrict__ Bg, float* __restrict__ Sg,
    float* __restrict__ ACSg) {
  const int bhc = blockIdx.x;
  const int c  = bhc & (NC - 1);
  const int bh = bhc >> 5;
  const int h  = bh & (NH - 1);
  const int b  = bh >> 4;
  __shared__ float sAcs[LB];
  __shared__ float sBd[LB][ND];
  __shared__ float sX[LB][PD];
  const int t = threadIdx.x;

  if (t < 64) {
    float v = Ag[((size_t)(b * SEQL) + c * LB + t) * NH + h];
#pragma unroll
    for (int d = 1; d < 64; d <<= 1) {
      float o = __shfl_up(v, d, 64);
      if (t >= d) v += o;
    }
    sAcs[t] = v;
    ACSg[(((size_t)b * NC + c) * NH + h) * LB + t] = v;
  }
  __syncthreads();
  const float total = sAcs[LB - 1];
  {
    const int l = t >> 2, q = t & 3;
    float4 b4 = *(const float4*)&Bg[((((size_t)(b * SEQL) + c * LB + l) * NH + h) * ND) + q * 4];
    const float dec = expf(total - sAcs[l]);
    b4.x *= dec; b4.y *= dec; b4.z *= dec; b4.w *= dec;
    ((float4*)sBd[l])[q] = b4;
  }
  {
    const int s = t >> 2, p0 = (t & 3) * 16;
    const float4* src = (const float4*)&Xg[((((size_t)(b * SEQL) + c * LB + s) * NH + h) * PD) + p0];
    float4* dst = (float4*)&sX[s][p0];
#pragma unroll
    for (int k = 0; k < 4; ++k) dst[k] = src[k];
  }
  __syncthreads();
  const int p = t >> 2, nq = t & 3;
  float4 acc = make_float4(0.f, 0.f, 0.f, 0.f);
#pragma unroll
  for (int l = 0; l < LB; ++l) {
    const float x = sX[l][p];
    const float4 b4 = ((const float4*)sBd[l])[nq];
    acc.x += x * b4.x; acc.y += x * b4.y; acc.z += x * b4.z; acc.w += x * b4.w;
  }
  ((float4*)&Sg[(((size_t)b * NC + c) * NH + h) * (PD * ND)])[t] = acc;
}

// ------------------------------------------------------------------
// K2: per (b,h): inter-chunk scan
// ------------------------------------------------------------------
__global__ __launch_bounds__(1024) void k2_scan(
    const float* __restrict__ Sg, const float* __restrict__ ACSg,
    float* __restrict__ STg) {
  const int bh = blockIdx.x;
  const int h = bh & (NH - 1);
  const int b = bh >> 4;
  __shared__ float sE[NC];
  const int t = threadIdx.x;
  if (t < NC)
    sE[t] = expf(ACSg[(((size_t)b * NC + t) * NH + h) * LB + (LB - 1)]);
  __syncthreads();
  float st = 0.f;
  for (int c = 0; c < NC; ++c) {
    const size_t off = (((size_t)b * NC + c) * NH + h) * (PD * ND) + t;
    STg[off] = st;
    st = st * sE[c] + Sg[off];
  }
}

// ------------------------------------------------------------------
// K3 (MFMA): per (b,h,c):
//   phase 1: D' = (B C^T) tiles -> M[l][s] = tril(exp(Acs_l - Acs_s) * CB)
//   phase 2: Y = M @ X + exp(Acs_l) * (C @ ST^T)
// ------------------------------------------------------------------
__global__ __launch_bounds__(256) void k3_out(
    const float* __restrict__ Xg, const float* __restrict__ Bg,
    const float* __restrict__ Cg, const float* __restrict__ ACSg,
    const float* __restrict__ STg, float* __restrict__ Yg) {
  const int bhc = blockIdx.x;
  const int c  = bhc & (NC - 1);
  const int bh = bhc >> 5;
  const int h  = bh & (NH - 1);
  const int b  = bh >> 4;

  __shared__ __align__(16) unsigned short sXt[PD][LB + 8];  // X^T[p][s], stride 144B (16B-mult)
  __shared__ __align__(16) unsigned short sM [LB][LB + 8];  // M[l][s]
  __shared__ __align__(16) unsigned short sB [LB][ND];
  __shared__ __align__(16) unsigned short sC [LB][ND];
  __shared__ __align__(16) unsigned short sST[PD][ND];      // ST[p][n]
  __shared__ float sE[LB];
  __shared__ float sR[LB];
  const int t = threadIdx.x;

  // ---------- staging ----------
  if (t < 64) {
    const float v = ACSg[(((size_t)b * NC + c) * NH + h) * LB + t];
    sE[t] = expf(v);
    sR[t] = expf(-v);
  }
  {
    const int row = t >> 2, q = (t & 3) * 4;
    const size_t gbase = (((size_t)(b * SEQL) + c * LB + row) * NH + h) * ND + q;
    float4 bv = *(const float4*)&Bg[gbase];
    float4 cv = *(const float4*)&Cg[gbase];
    ushort4 bu = { f2bf(bv.x), f2bf(bv.y), f2bf(bv.z), f2bf(bv.w) };
    ushort4 cu = { f2bf(cv.x), f2bf(cv.y), f2bf(cv.z), f2bf(cv.w) };
    *(ushort4*)&sB[row][q] = bu;
    *(ushort4*)&sC[row][q] = cu;
    float4 sv = *(const float4*)&STg[(((size_t)b * NC + c) * NH + h) * (PD * ND) + (size_t)t * 4];
    ushort4 su = { f2bf(sv.x), f2bf(sv.y), f2bf(sv.z), f2bf(sv.w) };
    *(ushort4*)&sST[row][q] = su;
  }
  {
    // X: each thread handles a 4x4 block, writes transposed with l-contiguous b64s
    const int p0 = (t & 15) * 4, l0 = (t >> 4) * 4;
    const size_t xb = (((size_t)(b * SEQL) + c * LB + l0) * NH + h) * PD + p0;
    const size_t rs = (size_t)NH * PD;
    float4 x0 = *(const float4*)&Xg[xb];
    float4 x1 = *(const float4*)&Xg[xb + rs];
    float4 x2 = *(const float4*)&Xg[xb + 2 * rs];
    float4 x3 = *(const float4*)&Xg[xb + 3 * rs];
    ushort4 w0 = { f2bf(x0.x), f2bf(x1.x), f2bf(x2.x), f2bf(x3.x) };
    ushort4 w1 = { f2bf(x0.y), f2bf(x1.y), f2bf(x2.y), f2bf(x3.y) };
    ushort4 w2 = { f2bf(x0.z), f2bf(x1.z), f2bf(x2.z), f2bf(x3.z) };
    ushort4 w3 = { f2bf(x0.w), f2bf(x1.w), f2bf(x2.w), f2bf(x3.w) };
    *(ushort4*)&sXt[p0 + 0][l0] = w0;
    *(ushort4*)&sXt[p0 + 1][l0] = w1;
    *(ushort4*)&sXt[p0 + 2][l0] = w2;
    *(ushort4*)&sXt[p0 + 3][l0] = w3;
  }
  __syncthreads();

  const int wv = t >> 6;     // wave id 0..3
  const int lane = t & 63;
  const int g = lane >> 4;   // k-group 0..3
  const int cc = lane & 15;

  // ---------- phase 1: build M (rows l-block = wv) ----------
  {
    const int l = wv * 16 + cc;
    const float el = sE[l];
    bf16x8 zf = {0,0,0,0,0,0,0,0};
    bf16x8 cf = zf;
    if (g < 2) cf = *(const bf16x8*)&sC[l][g * 8];
#pragma unroll
    for (int j = 0; j < 4; ++j) {
      const int s0 = j * 16 + g * 4;
      if (j <= wv) {
        bf16x8 bfr = zf;
        if (g < 2) bfr = *(const bf16x8*)&sB[j * 16 + cc][g * 8];
        f32x4 z4 = {0.f, 0.f, 0.f, 0.f};
        f32x4 d = __builtin_amdgcn_mfma_f32_16x16x32_bf16(bfr, cf, z4, 0, 0, 0);
        // lane holds D'[s_in=4g+r][l_in=cc]; s = s0 + r, l = 16*wv + cc
        float m0 = d[0] * el * sR[s0 + 0];
        float m1 = d[1] * el * sR[s0 + 1];
        float m2 = d[2] * el * sR[s0 + 2];
        float m3 = d[3] * el * sR[s0 + 3];
        if (j == wv) {   // diagonal tile: mask s > l
          if (s0 + 0 > l) m0 = 0.f;
          if (s0 + 1 > l) m1 = 0.f;
          if (s0 + 2 > l) m2 = 0.f;
          if (s0 + 3 > l) m3 = 0.f;
        }
        unsigned int u0 = (unsigned int)f2bf(m0) | ((unsigned int)f2bf(m1) << 16);
        unsigned int u1 = (unsigned int)f2bf(m2) | ((unsigned int)f2bf(m3) << 16);
        *(uint2*)&sM[l][s0] = make_uint2(u0, u1);
      } else {
        *(uint2*)&sM[l][s0] = make_uint2(0u, 0u);
      }
    }
  }
  __syncthreads();

  // ---------- phase 2: Y tiles (col p-block = wv) ----------
  {
    const int p = wv * 16 + cc;
    bf16x8 zf = {0,0,0,0,0,0,0,0};
    bf16x8 xf0 = *(const bf16x8*)&sXt[p][g * 8];
    bf16x8 xf1 = *(const bf16x8*)&sXt[p][32 + g * 8];
    bf16x8 stf = zf;
    if (g < 2) stf = *(const bf16x8*)&sST[p][g * 8];
#pragma unroll
    for (int w = 0; w < 4; ++w) {
      const int lr = w * 16 + cc;
      bf16x8 cf = zf;
      if (g < 2) cf = *(const bf16x8*)&sC[lr][g * 8];
      f32x4 z4 = {0.f, 0.f, 0.f, 0.f};
      f32x4 acc = __builtin_amdgcn_mfma_f32_16x16x32_bf16(cf, stf, z4, 0, 0, 0);
#pragma unroll
      for (int r = 0; r < 4; ++r) acc[r] *= sE[w * 16 + g * 4 + r];  // e_l per output row
      bf16x8 a0 = *(const bf16x8*)&sM[lr][g * 8];
      acc = __builtin_amdgcn_mfma_f32_16x16x32_bf16(a0, xf0, acc, 0, 0, 0);
      if (w >= 2) {   // s in [32,64) all-zero for row-tiles 0,1
        bf16x8 a1 = *(const bf16x8*)&sM[lr][32 + g * 8];
        acc = __builtin_amdgcn_mfma_f32_16x16x32_bf16(a1, xf1, acc, 0, 0, 0);
      }
      const size_t yb = (((size_t)(b * SEQL) + c * LB + w * 16 + g * 4) * NH + h) * PD + p;
      const size_t rs = (size_t)NH * PD;
#pragma unroll
      for (int r = 0; r < 4; ++r)
        Yg[yb + (size_t)r * rs] = acc[r];
    }
  }
}

extern "C" void kernel_launch(void* const* d_in, const int* in_sizes, int n_in,
                              void* d_out, int out_size, void* d_ws, size_t ws_size,
                              hipStream_t stream) {
  (void)in_sizes; (void)n_in; (void)out_size; (void)ws_size;
  const float* X = (const float*)d_in[0];
  const float* A = (const float*)d_in[1];
  const float* B = (const float*)d_in[2];
  const float* C = (const float*)d_in[3];
  float* Y = (float*)d_out;

  const size_t SZ = (size_t)BS * NC * NH * PD * ND;  // 524288 floats
  float* Sg   = (float*)d_ws;
  float* STg  = Sg + SZ;
  float* ACSg = STg + SZ;

  k1_state<<<BS * NH * NC, 256, 0, stream>>>(X, A, B, Sg, ACSg);
  k2_scan<<<BS * NH, 1024, 0, stream>>>(Sg, ACSg, STg);
  k3_out<<<BS * NH * NC, 256, 0, stream>>>(X, B, C, ACSg, STg, Y);
}

// Round 3
// 79.875 us; speedup vs baseline: 2.6197x; 1.4327x over previous
//
#include <hip/hip_runtime.h>

#define BS 16
#define SEQL 2048
#define NH 16
#define PD 64
#define ND 16
#define LB 64
#define NC 32   // SEQL / LB

typedef __attribute__((ext_vector_type(8))) short bf16x8;
typedef __attribute__((ext_vector_type(4))) float f32x4;

static __device__ __forceinline__ unsigned short f2bf(float x) {
  unsigned int u = __float_as_uint(x);
  unsigned int r = (u + 0x7FFFu + ((u >> 16) & 1u)) >> 16;  // RNE
  return (unsigned short)r;
}

// One block per (b,h). 512 threads = 8 waves. Sequential over 32 chunks,
// carrying inter-chunk state ST[64p][16n] in LDS (fp32 recurrence + bf16
// mirror, ping-pong). Per chunk:
//   M[l][s]   = tril( r_s * sum_n C'[l,n] B[s,n] ),  C' = e_l * C
//   Y[l][p]   = sum_n C'[l,n] ST[p,n] + sum_s M[l,s] X[s,p]
//   ST'[p][n] = ST[p][n]*e_tot + sum_l dec_l B[l,n] X[l,p]
__global__ __launch_bounds__(512, 2) void ssd_fused(
    const float* __restrict__ Xg, const float* __restrict__ Ag,
    const float* __restrict__ Bg, const float* __restrict__ Cg,
    float* __restrict__ Yg) {
  const int h = blockIdx.x & (NH - 1);
  const int b = blockIdx.x >> 4;
  const int t = threadIdx.x;
  const int w = t >> 6;
  const int lane = t & 63;
  const int g = lane >> 4;     // k-group 0..3
  const int cc = lane & 15;

  __shared__ __align__(16) unsigned short sXt[PD][LB + 8];   // X^T[p][l] bf16
  __shared__ __align__(16) unsigned short sM [LB][LB + 8];   // M[l][s] bf16
  __shared__ __align__(16) unsigned short sB [LB][ND + 8];   // B[l][n] bf16
  __shared__ __align__(16) unsigned short sC [LB][ND + 8];   // C'[l][n] bf16
  __shared__ __align__(16) unsigned short sBdT[ND][LB + 8];  // (dec*B)^T[n][l] bf16
  __shared__ __align__(16) float          sSTf[2][PD][ND + 4]; // ST fp32 ping-pong
  __shared__ __align__(16) unsigned short sSTb[2][PD][ND + 8]; // ST bf16 mirror

  // zero initial state (read at c=0)
  for (int i = t; i < PD * (ND + 4); i += 512) ((float*)sSTf[0])[i] = 0.f;
  for (int i = t; i < PD * (ND + 8); i += 512) ((unsigned short*)sSTb[0])[i] = 0;

  // prefetch register staging
  const int xl0 = (t >> 4) * 2, xp0 = (t & 15) * 4;   // X: 2 rows x float4
  const int bl  = t >> 3,       bn0 = (t & 7) * 2;    // B/C: 1 row x float2
  float4 px0, px1; float2 pb2, pc2; float pa;

#define PREF(cc_) do { \
    const size_t s0_ = (size_t)(b * SEQL + (cc_) * LB); \
    px0 = *(const float4*)&Xg[(s0_ + xl0) * (NH * PD) + h * PD + xp0]; \
    px1 = *(const float4*)&Xg[(s0_ + xl0 + 1) * (NH * PD) + h * PD + xp0]; \
    pb2 = *(const float2*)&Bg[(s0_ + bl) * (NH * ND) + h * ND + bn0]; \
    pc2 = *(const float2*)&Cg[(s0_ + bl) * (NH * ND) + h * ND + bn0]; \
    pa  = Ag[(s0_ + lane) * NH + h]; \
  } while (0)

  PREF(0);

  for (int c = 0; c < NC; ++c) {
    // ---- per-wave redundant cumsum of A (all 8 waves) ----
    float v = pa;
#pragma unroll
    for (int d = 1; d < 64; d <<= 1) {
      float o = __shfl_up(v, d, 64);
      if (lane >= d) v += o;
    }
    const float acs = v;
    const float er = expf(acs);          // e_l (lane l)   <= 1
    const float rr = expf(-acs);         // r_s (lane s)
    const float etot = __shfl(er, 63);   // exp(A_total)

    // ---- staging writes (bf16) ----
    {
#pragma unroll
      for (int j = 0; j < 4; ++j) {
        const float xa = (&px0.x)[j], xb = (&px1.x)[j];
        *(unsigned int*)&sXt[xp0 + j][xl0] =
            (unsigned int)f2bf(xa) | ((unsigned int)f2bf(xb) << 16);
      }
      const float el = __shfl(er, bl);
      const float dl = etot * __shfl(rr, bl);   // dec_l = exp(Atot - acs_l)
      *(unsigned int*)&sB[bl][bn0] =
          (unsigned int)f2bf(pb2.x) | ((unsigned int)f2bf(pb2.y) << 16);
      *(unsigned int*)&sC[bl][bn0] =
          (unsigned int)f2bf(el * pc2.x) | ((unsigned int)f2bf(el * pc2.y) << 16);
      sBdT[bn0][bl]     = f2bf(dl * pb2.x);
      sBdT[bn0 + 1][bl] = f2bf(dl * pb2.y);
    }
    if (c + 1 < NC) PREF(c + 1);   // loads fly under this chunk's compute
    __syncthreads();

    // ---- phase 1: M tiles. wave w -> l-block w&3, s-blocks {0,1} or {2,3}
    {
      const int lb1 = w & 3;
      const int l = lb1 * 16 + cc;
      bf16x8 zf = {0, 0, 0, 0, 0, 0, 0, 0};
      bf16x8 cf = zf;
      if (g < 2) cf = *(const bf16x8*)&sC[l][g * 8];
#pragma unroll
      for (int ii = 0; ii < 2; ++ii) {
        const int sb = (w < 4 ? 0 : 2) + ii;
        uint2 out = make_uint2(0u, 0u);
        if (sb <= lb1) {
          bf16x8 bfr = zf;
          if (g < 2) bfr = *(const bf16x8*)&sB[sb * 16 + cc][g * 8];
          f32x4 z4 = {0.f, 0.f, 0.f, 0.f};
          f32x4 d = __builtin_amdgcn_mfma_f32_16x16x32_bf16(bfr, cf, z4, 0, 0, 0);
          // lane holds D'[s = sb*16+4g+r][l]
          float m[4];
#pragma unroll
          for (int r = 0; r < 4; ++r) {
            const int srow = sb * 16 + 4 * g + r;
            m[r] = d[r] * __shfl(rr, srow);
            if (sb == lb1 && (4 * g + r) > cc) m[r] = 0.f;
          }
          out.x = (unsigned int)f2bf(m[0]) | ((unsigned int)f2bf(m[1]) << 16);
          out.y = (unsigned int)f2bf(m[2]) | ((unsigned int)f2bf(m[3]) << 16);
        }
        *(uint2*)&sM[l][sb * 16 + g * 4] = out;
      }
    }
    __syncthreads();

    const int cur = c & 1, nxt = cur ^ 1;
    if (w < 4) {
      // ---- phase 2: Y tiles. wave = l-block, loop p-blocks ----
      const int lb = w;
      const int l = lb * 16 + cc;
      bf16x8 zf = {0, 0, 0, 0, 0, 0, 0, 0};
      bf16x8 cf = zf;
      if (g < 2) cf = *(const bf16x8*)&sC[l][g * 8];
      bf16x8 a0 = *(const bf16x8*)&sM[l][g * 8];
      bf16x8 a1 = zf;
      if (lb >= 2) a1 = *(const bf16x8*)&sM[l][32 + g * 8];
#pragma unroll
      for (int pb = 0; pb < 4; ++pb) {
        const int p = pb * 16 + cc;
        bf16x8 stf = zf;
        if (g < 2) stf = *(const bf16x8*)&sSTb[cur][p][g * 8];
        f32x4 acc = {0.f, 0.f, 0.f, 0.f};
        acc = __builtin_amdgcn_mfma_f32_16x16x32_bf16(cf, stf, acc, 0, 0, 0);
        bf16x8 xf0 = *(const bf16x8*)&sXt[p][g * 8];
        acc = __builtin_amdgcn_mfma_f32_16x16x32_bf16(a0, xf0, acc, 0, 0, 0);
        if (lb >= 2) {
          bf16x8 xf1 = *(const bf16x8*)&sXt[p][32 + g * 8];
          acc = __builtin_amdgcn_mfma_f32_16x16x32_bf16(a1, xf1, acc, 0, 0, 0);
        }
        const size_t yb =
            ((size_t)(b * SEQL + c * LB + lb * 16 + 4 * g)) * (NH * PD) + h * PD + p;
#pragma unroll
        for (int r = 0; r < 4; ++r)
          Yg[yb + (size_t)r * (NH * PD)] = acc[r];
      }
    } else {
      // ---- phase S: S[n][p] = (dec*B)^T @ X ; ST update (ping-pong) ----
      const int pb = w - 4;
      const int p = pb * 16 + cc;
      bf16x8 ad0 = *(const bf16x8*)&sBdT[cc][g * 8];
      bf16x8 ad1 = *(const bf16x8*)&sBdT[cc][32 + g * 8];
      bf16x8 xt0 = *(const bf16x8*)&sXt[p][g * 8];
      bf16x8 xt1 = *(const bf16x8*)&sXt[p][32 + g * 8];
      f32x4 acc = {0.f, 0.f, 0.f, 0.f};
      acc = __builtin_amdgcn_mfma_f32_16x16x32_bf16(ad0, xt0, acc, 0, 0, 0);
      acc = __builtin_amdgcn_mfma_f32_16x16x32_bf16(ad1, xt1, acc, 0, 0, 0);
      // lane holds S[n = 4g+r][p]
      float4 old = *(const float4*)&sSTf[cur][p][4 * g];
      float4 nw;
      nw.x = old.x * etot + acc[0];
      nw.y = old.y * etot + acc[1];
      nw.z = old.z * etot + acc[2];
      nw.w = old.w * etot + acc[3];
      *(float4*)&sSTf[nxt][p][4 * g] = nw;
      uint2 ub;
      ub.x = (unsigned int)f2bf(nw.x) | ((unsigned int)f2bf(nw.y) << 16);
      ub.y = (unsigned int)f2bf(nw.z) | ((unsigned int)f2bf(nw.w) << 16);
      *(uint2*)&sSTb[nxt][p][4 * g] = ub;
    }
    __syncthreads();
  }
#undef PREF
}

extern "C" void kernel_launch(void* const* d_in, const int* in_sizes, int n_in,
                              void* d_out, int out_size, void* d_ws, size_t ws_size,
                              hipStream_t stream) {
  (void)in_sizes; (void)n_in; (void)out_size; (void)d_ws; (void)ws_size;
  const float* X = (const float*)d_in[0];
  const float* A = (const float*)d_in[1];
  const float* B = (const float*)d_in[2];
  const float* C = (const float*)d_in[3];
  float* Y = (float*)d_out;
  ssd_fused<<<BS * NH, 512, 0, stream>>>(X, A, B, C, Y);
}